// Round 2
// baseline (53265.820 us; speedup 1.0000x reference)
//
#include <hip/hip_runtime.h>
#include <hip/hip_bf16.h>
#include <math.h>

// ---------------------------------------------------------------------------
// Round 2: single persistent cooperative kernel for the 200-step recurrence
// (3 grid barriers/step), bf16 MFMA for LSTM1/LSTM2/output-projection,
// fp32 accumulate, fp32 cell states. States stored bf16 [n][k] row-major so
// MFMA fragments are direct 16B global loads (no LDS staging).
//
// MFMA semantics used (HW-verified direction):
//   D = MFMA16(a, b):  D[i][j] = sum_k a_row(i)[k] * b_row(j)[k]
//   a rows: i = reg-dim (4*(lane>>4)+reg), b rows: j = lane&15.
//   Both frags load 8 contiguous bf16 at k0 + (lane>>4)*8 -> identical k-map
//   on both operands => result independent of HW's internal k permutation.
// ---------------------------------------------------------------------------

#define NB    64
#define TENC  500
#define TDEC  200
#define EMBD  512
#define HID   1024
#define KSZ   128
#define VSZ   128
#define VOCAB 10000
#define K1    1664
#define K2    1152
#define NWG   256
#define NTH   512

typedef __bf16 bf16x8 __attribute__((ext_vector_type(8)));
typedef float f32x4 __attribute__((ext_vector_type(4)));
#define MFMA16(a, b, c) __builtin_amdgcn_mfma_f32_16x16x32_bf16((a), (b), (c), 0, 0, 0)

// ws layout (bytes)
constexpr size_t OFF_BAR   = 0;         // cnt[8*32] u32 + rel
constexpr size_t OFF_H1    = 4096;      // bf16 [2][64][1024]
constexpr size_t OFF_H2    = 266240;    // bf16 [2][64][128]
constexpr size_t OFF_CTX   = 299008;    // bf16 [64][128]
constexpr size_t OFF_C1    = 315392;    // f32 [64][1024]
constexpr size_t OFF_C2    = 577536;    // f32 [64][128]
constexpr size_t ZERO_END  = 610304;
constexpr size_t OFF_BS1   = 610304;    // f32 [4096]
constexpr size_t OFF_BS2   = 626688;    // f32 [512]
constexpr size_t OFF_W1    = 628736;    // bf16 [4096][1664]
constexpr size_t OFF_W2    = 14260224;  // bf16 [512][1152]
constexpr size_t OFF_WOUT  = 15439872;  // bf16 [10000][256]
constexpr size_t OFF_XEMB  = 20559872;  // bf16 [200][64][512]
constexpr size_t OFF_H2C   = 33667072;  // bf16 [12800][256]
constexpr size_t BASE_END  = 40220672;
constexpr size_t OFF_KEYBF = 40220672;  // bf16 [64][500][128] (optional)
constexpr size_t OFF_VALBF = 48412672;  // bf16 [64][500][128] (optional)
constexpr size_t KV_END    = 56604672;

__device__ __forceinline__ float sigm(float x) { return 1.0f / (1.0f + __expf(-x)); }
__device__ __forceinline__ float ftanh(float x) {
  float ax = fabsf(x);
  float e = __expf(2.0f * ax);
  float tv = 1.0f - 2.0f / (e + 1.0f);
  return copysignf(tv, x);
}
__device__ __forceinline__ float bf2f(unsigned u) { return __uint_as_float(u << 16); }
__device__ __forceinline__ bf16x8 ldfrag(const __hip_bfloat16* p) {
  return *reinterpret_cast<const bf16x8*>(p);
}

// ------------------------------------------------------------- prep kernels
__global__ __launch_bounds__(256) void k_prep_w1(const float* __restrict__ Wih1,
                                                 const float* __restrict__ Whh1,
                                                 const float* __restrict__ bih1,
                                                 const float* __restrict__ bhh1,
                                                 __hip_bfloat16* __restrict__ W1bf,
                                                 float* __restrict__ bsum1) {
  int r = blockIdx.x;
  const float* wi = Wih1 + (size_t)r * 640;
  const float* wh = Whh1 + (size_t)r * 1024;
  for (int k = threadIdx.x; k < K1; k += 256)
    W1bf[(size_t)r * K1 + k] = __float2bfloat16(k < 640 ? wi[k] : wh[k - 640]);
  if (threadIdx.x == 0) bsum1[r] = bih1[r] + bhh1[r];
}

__global__ __launch_bounds__(256) void k_prep_w2(const float* __restrict__ Wih2,
                                                 const float* __restrict__ Whh2,
                                                 const float* __restrict__ bih2,
                                                 const float* __restrict__ bhh2,
                                                 __hip_bfloat16* __restrict__ W2bf,
                                                 float* __restrict__ bsum2) {
  int r = blockIdx.x;
  const float* wi = Wih2 + (size_t)r * 1024;
  const float* wh = Whh2 + (size_t)r * 128;
  for (int k = threadIdx.x; k < K2; k += 256)
    W2bf[(size_t)r * K2 + k] = __float2bfloat16(k < 1024 ? wi[k] : wh[k - 1024]);
  if (threadIdx.x == 0) bsum2[r] = bih2[r] + bhh2[r];
}

__global__ __launch_bounds__(256) void k_prep_wout(const float* __restrict__ Wout,
                                                   __hip_bfloat16* __restrict__ Woutbf) {
  int r0 = blockIdx.x * 16;
  for (int idx = threadIdx.x; idx < 16 * 256; idx += 256) {
    int r = r0 + (idx >> 8), k = idx & 255;
    Woutbf[(size_t)r * 256 + k] = __float2bfloat16(Wout[(size_t)r * 256 + k]);
  }
}

__global__ __launch_bounds__(256) void k_gather(const int* __restrict__ text,
                                                const float* __restrict__ emb,
                                                __hip_bfloat16* __restrict__ xembbf) {
  int t = blockIdx.x;
  __shared__ int tok[NB];
  if (threadIdx.x < NB) tok[threadIdx.x] = text[threadIdx.x * TDEC + t];
  __syncthreads();
  for (int idx = threadIdx.x; idx < NB * EMBD; idx += 256) {
    int n = idx >> 9, k = idx & 511;
    xembbf[((size_t)t * NB + n) * EMBD + k] =
        __float2bfloat16(emb[(size_t)tok[n] * EMBD + k]);
  }
}

__global__ __launch_bounds__(256) void k_prep_kv(const float* __restrict__ key,
                                                 const float* __restrict__ value,
                                                 __hip_bfloat16* __restrict__ keybf,
                                                 __hip_bfloat16* __restrict__ valbf) {
  int gsz = gridDim.x * 256;
  for (size_t i = blockIdx.x * 256 + threadIdx.x; i < (size_t)NB * TENC * KSZ; i += gsz) {
    keybf[i] = __float2bfloat16(key[i]);
    valbf[i] = __float2bfloat16(value[i]);
  }
}

// ------------------------------------------------------------- grid barrier
__device__ __forceinline__ void gbar(unsigned* cnt, unsigned* rel, int ep, int wg) {
  __syncthreads();
  int tid = threadIdx.x;
  if (tid == 0) {
    __threadfence();
    __hip_atomic_fetch_add(&cnt[(wg & 7) << 5], 1u, __ATOMIC_ACQ_REL,
                           __HIP_MEMORY_SCOPE_AGENT);
  }
  if (wg == 0 && tid < 64) {
    unsigned need = (unsigned)ep << 5;  // 32 arrivals per counter
    for (;;) {
      unsigned v = __hip_atomic_load(&cnt[(tid & 7) << 5], __ATOMIC_ACQUIRE,
                                     __HIP_MEMORY_SCOPE_AGENT);
      if (__all((int)(v >= need))) break;
      __builtin_amdgcn_s_sleep(1);
    }
    if (tid == 0)
      __hip_atomic_store(rel, (unsigned)ep, __ATOMIC_RELEASE, __HIP_MEMORY_SCOPE_AGENT);
  }
  if (tid == 0) {
    while (__hip_atomic_load(rel, __ATOMIC_ACQUIRE, __HIP_MEMORY_SCOPE_AGENT) <
           (unsigned)ep)
      __builtin_amdgcn_s_sleep(1);
    __threadfence();
  }
  __syncthreads();
}

// ------------------------------------------------------- persistent kernel
struct LA {
  const float* key;
  const float* value;
  const int* slen;
  const __hip_bfloat16* keybf;
  const __hip_bfloat16* valbf;
  int use_kvbf;
  const __hip_bfloat16* W1bf;
  const __hip_bfloat16* W2bf;
  const __hip_bfloat16* xembbf;
  const float* bsum1;
  const float* bsum2;
  __hip_bfloat16* h1bf;   // [2][64][1024]
  __hip_bfloat16* h2bf;   // [2][64][128]
  __hip_bfloat16* ctxbf;  // [64][128]
  __hip_bfloat16* h2cbf;  // [12800][256]
  float* c1;              // [64][1024]
  float* c2;              // [64][128]
  unsigned* bar_cnt;
  unsigned* bar_rel;
};

__global__ __launch_bounds__(NTH) void k_loop(LA a) {
  const int wg = blockIdx.x;
  const int tid = threadIdx.x;
  const int lane = tid & 63;
  const int wid = tid >> 6;        // 0..7
  const int ln15 = lane & 15;
  const int lg = lane >> 4;        // 0..3
  const int ko = lg * 8;           // k sub-offset within 32-wide step
  const int bg = wid & 3;          // batch-group (16 each)
  const int kh = wid >> 2;         // K-half

  __shared__ float h2s[128];
  __shared__ float e_lds[512];
  __shared__ float red[512];
  __shared__ float ctxp[4][128];
  __shared__ float part[4][64][4];
  __shared__ float gl[4][16][20];

  int ep = 0;
  for (int t = 0; t < TDEC; ++t) {
    const int cur = t & 1, nxt = cur ^ 1;

    // ---------------- phase A: attention (wg 0..63, one batch each)
    if (wg < 64) {
      const int n = wg;
      const int len = a.slen[n];
      if (tid < 128) h2s[tid] = __bfloat162float(a.h2bf[(size_t)cur * 8192 + n * 128 + tid]);
      __syncthreads();
      float e;
      if (tid < TENC) {
        if (tid < len) {
          float acc = 0.f;
          if (a.use_kvbf) {
            const __hip_bfloat16* kr = a.keybf + ((size_t)n * TENC + tid) * KSZ;
            #pragma unroll 4
            for (int k = 0; k < KSZ; k += 8) {
              uint4 u = *reinterpret_cast<const uint4*>(kr + k);
              acc += bf2f(u.x & 0xffffu) * h2s[k]     + bf2f(u.x >> 16) * h2s[k + 1]
                   + bf2f(u.y & 0xffffu) * h2s[k + 2] + bf2f(u.y >> 16) * h2s[k + 3]
                   + bf2f(u.z & 0xffffu) * h2s[k + 4] + bf2f(u.z >> 16) * h2s[k + 5]
                   + bf2f(u.w & 0xffffu) * h2s[k + 6] + bf2f(u.w >> 16) * h2s[k + 7];
            }
          } else {
            const float* kr = a.key + ((size_t)n * TENC + tid) * KSZ;
            #pragma unroll 8
            for (int k = 0; k < KSZ; k += 4) {
              float4 kv = *reinterpret_cast<const float4*>(kr + k);
              acc += kv.x * h2s[k] + kv.y * h2s[k + 1] + kv.z * h2s[k + 2] + kv.w * h2s[k + 3];
            }
          }
          e = acc;
        } else {
          e = -1e9f;
        }
      } else {
        e = -INFINITY;
      }
      red[tid] = e;
      __syncthreads();
      for (int s = 256; s > 0; s >>= 1) {
        if (tid < s) red[tid] = fmaxf(red[tid], red[tid + s]);
        __syncthreads();
      }
      float m = red[0];
      __syncthreads();
      float ev = __expf(e - m);
      e_lds[tid] = ev;
      red[tid] = ev;
      __syncthreads();
      for (int s = 256; s > 0; s >>= 1) {
        if (tid < s) red[tid] += red[tid + s];
        __syncthreads();
      }
      float inv = 1.f / red[0];
      int v = tid & 127, q = tid >> 7;
      float acc = 0.f;
      for (int p = q * 125; p < q * 125 + 125; ++p) {
        float w = e_lds[p];
        if (w != 0.f) {
          float vv = a.use_kvbf
                         ? __bfloat162float(a.valbf[((size_t)n * TENC + p) * VSZ + v])
                         : a.value[((size_t)n * TENC + p) * VSZ + v];
          acc += w * vv;
        }
      }
      ctxp[q][v] = acc;
      __syncthreads();
      if (tid < 128) {
        float c = (ctxp[0][tid] + ctxp[1][tid] + ctxp[2][tid] + ctxp[3][tid]) * inv;
        __hip_bfloat16 cb = __float2bfloat16(c);
        a.ctxbf[n * 128 + tid] = cb;
        a.h2cbf[((size_t)t * NB + n) * 256 + 128 + tid] = cb;
      }
    }
    gbar(a.bar_cnt, a.bar_rel, ++ep, wg);

    // ---------------- phase B: LSTM1 (all 256 wgs, 4 h-dims each)
    {
      const int d0 = wg * 4;
      const int j = ln15;
      const int wr = (j & 3) * HID + d0 + (j >> 2);  // W1 row for this lane
      const __hip_bfloat16* wp = a.W1bf + (size_t)wr * K1;
      const int n = bg * 16 + ln15;
      const __hip_bfloat16* xe = a.xembbf + ((size_t)t * NB + n) * EMBD;
      const __hip_bfloat16* cx = a.ctxbf + n * 128;
      const __hip_bfloat16* h1 = a.h1bf + (size_t)cur * 65536 + n * 1024;
      f32x4 acc = {0.f, 0.f, 0.f, 0.f};
      if (kh == 0) {
        #pragma unroll 4
        for (int s = 0; s < 16; ++s)
          acc = MFMA16(ldfrag(xe + s * 32 + ko), ldfrag(wp + s * 32 + ko), acc);
        #pragma unroll
        for (int s = 0; s < 4; ++s)
          acc = MFMA16(ldfrag(cx + s * 32 + ko), ldfrag(wp + 512 + s * 32 + ko), acc);
        #pragma unroll
        for (int s = 0; s < 6; ++s)
          acc = MFMA16(ldfrag(h1 + s * 32 + ko), ldfrag(wp + 640 + s * 32 + ko), acc);
      } else {
        #pragma unroll 4
        for (int s = 0; s < 26; ++s)
          acc = MFMA16(ldfrag(h1 + 192 + s * 32 + ko), ldfrag(wp + 832 + s * 32 + ko), acc);
      }
      if (kh == 1) *reinterpret_cast<f32x4*>(&part[bg][lane][0]) = acc;
      __syncthreads();
      if (kh == 0) {
        f32x4 pr = *reinterpret_cast<const f32x4*>(&part[bg][lane][0]);
        #pragma unroll
        for (int r = 0; r < 4; ++r) gl[bg][lg * 4 + r][j] = acc[r] + pr[r];
      }
      __syncthreads();
      if (tid < 256) {
        int nn = tid >> 2, dsub = tid & 3;
        int bgg = nn >> 4, ii = nn & 15;
        float4 g4 = *reinterpret_cast<const float4*>(&gl[bgg][ii][dsub * 4]);
        int d = d0 + dsub;
        float I = sigm(g4.x + a.bsum1[d]);
        float F = sigm(g4.y + a.bsum1[HID + d]);
        float G = ftanh(g4.z + a.bsum1[2 * HID + d]);
        float O = sigm(g4.w + a.bsum1[3 * HID + d]);
        float c = F * a.c1[nn * 1024 + d] + I * G;
        a.c1[nn * 1024 + d] = c;
        a.h1bf[(size_t)nxt * 65536 + nn * 1024 + d] = __float2bfloat16(O * ftanh(c));
      }
    }
    gbar(a.bar_cnt, a.bar_rel, ++ep, wg);

    // ---------------- phase C: LSTM2 (wg 0..31, 4 h-dims each)
    if (wg < 32) {
      const int d0 = wg * 4;
      const int j = ln15;
      const int wr = (j & 3) * KSZ + d0 + (j >> 2);
      const __hip_bfloat16* wp = a.W2bf + (size_t)wr * K2;
      const int n = bg * 16 + ln15;
      const __hip_bfloat16* h1n = a.h1bf + (size_t)nxt * 65536 + n * 1024;
      const __hip_bfloat16* h2p = a.h2bf + (size_t)cur * 8192 + n * 128;
      f32x4 acc = {0.f, 0.f, 0.f, 0.f};
      if (kh == 0) {
        #pragma unroll 4
        for (int s = 0; s < 18; ++s)
          acc = MFMA16(ldfrag(h1n + s * 32 + ko), ldfrag(wp + s * 32 + ko), acc);
      } else {
        #pragma unroll 4
        for (int s = 0; s < 14; ++s)
          acc = MFMA16(ldfrag(h1n + 576 + s * 32 + ko), ldfrag(wp + 576 + s * 32 + ko), acc);
        #pragma unroll
        for (int s = 0; s < 4; ++s)
          acc = MFMA16(ldfrag(h2p + s * 32 + ko), ldfrag(wp + 1024 + s * 32 + ko), acc);
      }
      if (kh == 1) *reinterpret_cast<f32x4*>(&part[bg][lane][0]) = acc;
      __syncthreads();
      if (kh == 0) {
        f32x4 pr = *reinterpret_cast<const f32x4*>(&part[bg][lane][0]);
        #pragma unroll
        for (int r = 0; r < 4; ++r) gl[bg][lg * 4 + r][j] = acc[r] + pr[r];
      }
      __syncthreads();
      if (tid < 256) {
        int nn = tid >> 2, dsub = tid & 3;
        int bgg = nn >> 4, ii = nn & 15;
        float4 g4 = *reinterpret_cast<const float4*>(&gl[bgg][ii][dsub * 4]);
        int d = d0 + dsub;
        float I = sigm(g4.x + a.bsum2[d]);
        float F = sigm(g4.y + a.bsum2[KSZ + d]);
        float G = ftanh(g4.z + a.bsum2[2 * KSZ + d]);
        float O = sigm(g4.w + a.bsum2[3 * KSZ + d]);
        float c = F * a.c2[nn * 128 + d] + I * G;
        a.c2[nn * 128 + d] = c;
        __hip_bfloat16 hb = __float2bfloat16(O * ftanh(c));
        a.h2bf[(size_t)nxt * 8192 + nn * 128 + d] = hb;
        a.h2cbf[((size_t)t * NB + nn) * 256 + d] = hb;
      }
    }
    gbar(a.bar_cnt, a.bar_rel, ++ep, wg);
  }
}

// ------------------------------------------------------ output projection
__global__ __launch_bounds__(256) void k_out(const __hip_bfloat16* __restrict__ h2cbf,
                                             const __hip_bfloat16* __restrict__ Woutbf,
                                             const float* __restrict__ bout,
                                             float* __restrict__ out) {
  int tid = threadIdx.x;
  int w = tid >> 6, lane = tid & 63;
  int ln15 = lane & 15, lg = lane >> 4, ko = lg * 8;
  int c0 = blockIdx.x * 64, m0 = blockIdx.y * 64;
  const __hip_bfloat16* ap = h2cbf + (size_t)(m0 + w * 16 + ln15) * 256;
  bf16x8 afr[8];
  #pragma unroll
  for (int kk = 0; kk < 8; ++kk) afr[kk] = ldfrag(ap + kk * 32 + ko);
  union U16 { uint4 u; bf16x8 v; };
  #pragma unroll
  for (int s = 0; s < 4; ++s) {
    int r = c0 + s * 16 + ln15;
    const __hip_bfloat16* bp = Woutbf + (size_t)r * 256;
    bool ok = r < VOCAB;
    f32x4 acc = {0.f, 0.f, 0.f, 0.f};
    #pragma unroll
    for (int kk = 0; kk < 8; ++kk) {
      U16 bv;
      bv.u = make_uint4(0, 0, 0, 0);
      if (ok) bv.v = ldfrag(bp + kk * 32 + ko);
      acc = MFMA16(afr[kk], bv.v, acc);
    }
    int c = c0 + s * 16 + ln15;
    if (c < VOCAB) {
      float bb = bout[c];
      #pragma unroll
      for (int reg = 0; reg < 4; ++reg) {
        int m = m0 + w * 16 + 4 * lg + reg;
        int n = m & 63, tt = m >> 6;
        out[((size_t)n * TDEC + tt) * VOCAB + c] = acc[reg] + bb;
      }
    }
  }
}

// ---------------------------------------------------------------------------
extern "C" void kernel_launch(void* const* d_in, const int* in_sizes, int n_in,
                              void* d_out, int out_size, void* d_ws, size_t ws_size,
                              hipStream_t stream) {
  (void)in_sizes; (void)n_in; (void)out_size;
  const float* key   = (const float*)d_in[0];
  const float* value = (const float*)d_in[1];
  const int*   slen  = (const int*)d_in[2];
  const int*   text  = (const int*)d_in[3];
  const float* emb   = (const float*)d_in[4];
  const float* Wih1  = (const float*)d_in[5];
  const float* Whh1  = (const float*)d_in[6];
  const float* bih1  = (const float*)d_in[7];
  const float* bhh1  = (const float*)d_in[8];
  const float* Wih2  = (const float*)d_in[9];
  const float* Whh2  = (const float*)d_in[10];
  const float* bih2  = (const float*)d_in[11];
  const float* bhh2  = (const float*)d_in[12];
  const float* Wout  = (const float*)d_in[13];
  const float* bout  = (const float*)d_in[14];
  float* out = (float*)d_out;
  char* ws = (char*)d_ws;

  __hip_bfloat16* W1bf   = (__hip_bfloat16*)(ws + OFF_W1);
  __hip_bfloat16* W2bf   = (__hip_bfloat16*)(ws + OFF_W2);
  __hip_bfloat16* Woutbf = (__hip_bfloat16*)(ws + OFF_WOUT);
  __hip_bfloat16* xembbf = (__hip_bfloat16*)(ws + OFF_XEMB);
  __hip_bfloat16* h2cbf  = (__hip_bfloat16*)(ws + OFF_H2C);
  float* bsum1 = (float*)(ws + OFF_BS1);
  float* bsum2 = (float*)(ws + OFF_BS2);

  int use_kvbf = (ws_size >= KV_END) ? 1 : 0;
  __hip_bfloat16* keybf = (__hip_bfloat16*)(ws + OFF_KEYBF);
  __hip_bfloat16* valbf = (__hip_bfloat16*)(ws + OFF_VALBF);

  hipMemsetAsync(d_ws, 0, ZERO_END, stream);
  k_prep_w1<<<4096, 256, 0, stream>>>(Wih1, Whh1, bih1, bhh1, W1bf, bsum1);
  k_prep_w2<<<512, 256, 0, stream>>>(Wih2, Whh2, bih2, bhh2, W2bf, bsum2);
  k_prep_wout<<<625, 256, 0, stream>>>(Wout, Woutbf);
  k_gather<<<TDEC, 256, 0, stream>>>(text, emb, xembbf);
  if (use_kvbf) k_prep_kv<<<2048, 256, 0, stream>>>(key, value, keybf, valbf);

  LA la;
  la.key = key; la.value = value; la.slen = slen;
  la.keybf = keybf; la.valbf = valbf; la.use_kvbf = use_kvbf;
  la.W1bf = W1bf; la.W2bf = W2bf; la.xembbf = xembbf;
  la.bsum1 = bsum1; la.bsum2 = bsum2;
  la.h1bf = (__hip_bfloat16*)(ws + OFF_H1);
  la.h2bf = (__hip_bfloat16*)(ws + OFF_H2);
  la.ctxbf = (__hip_bfloat16*)(ws + OFF_CTX);
  la.h2cbf = h2cbf;
  la.c1 = (float*)(ws + OFF_C1);
  la.c2 = (float*)(ws + OFF_C2);
  la.bar_cnt = (unsigned*)(ws + OFF_BAR);
  la.bar_rel = (unsigned*)(ws + OFF_BAR + 1024);

  void* args[] = {&la};
  hipLaunchCooperativeKernel((void*)k_loop, dim3(NWG), dim3(NTH), args, 0, stream);

  k_out<<<dim3(157, 200), 256, 0, stream>>>(h2cbf, Woutbf, bout, out);
}

// Round 3
// 29248.520 us; speedup vs baseline: 1.8211x; 1.8211x over previous
//
#include <hip/hip_runtime.h>
#include <hip/hip_bf16.h>
#include <math.h>

// ---------------------------------------------------------------------------
// Round 3: persistent cooperative kernel, RELAXED-atomic grid barrier (no
// buffer_inv storms), 2 barriers/step (LSTM2+attention fused per-batch-pair,
// h2/c2 in LDS, c1 in registers). Cross-XCD state (h1, ctx, barrier) moves
// via relaxed agent-scope atomics (sc1, coherence-point); weights/KV/xemb
// stay normally cached in L2 (never invalidated).
// ---------------------------------------------------------------------------

#define NB    64
#define TENC  500
#define TDEC  200
#define EMBD  512
#define HID   1024
#define KSZ   128
#define VSZ   128
#define VOCAB 10000
#define K1    1664
#define K2    1152
#define NWG   64
#define NTH   512

typedef __bf16 bf16x8 __attribute__((ext_vector_type(8)));
typedef float f32x4 __attribute__((ext_vector_type(4)));
typedef unsigned long long u64;
#define MFMA16(a, b, c) __builtin_amdgcn_mfma_f32_16x16x32_bf16((a), (b), (c), 0, 0, 0)

// ws layout (bytes)
constexpr size_t OFF_BAR   = 0;          // cnt 8x64B @0, rel u32 @1024
constexpr size_t OFF_H1    = 4096;       // bf16 [2][64][1024] = 262144
constexpr size_t OFF_CTX   = 266240;     // bf16 [64][128] = 16384
constexpr size_t OFF_BS1   = 282624;     // f32 [4096]
constexpr size_t OFF_BS2   = 299008;     // f32 [512]
constexpr size_t OFF_W2T   = 301056;     // bf16 [144][512][8] = 1179648
constexpr size_t OFF_H2C   = 1480704;    // bf16 [12800][256] = 6553600
constexpr size_t OFF_W1    = 8034304;    // bf16 [4096][1664] = 13631488
constexpr size_t OFF_WOUT  = 21665792;   // bf16 [10000][256] = 5120000
constexpr size_t OFF_XEMB  = 26785792;   // bf16 [200][64][512] = 13107200
constexpr size_t BASE_END  = 39892992;
constexpr size_t OFF_KEYBF = 39892992;   // bf16 [64][500][128]
constexpr size_t OFF_VALBF = 48084992;   // bf16 [64][500][128]
constexpr size_t KV_END    = 56276992;

__device__ __forceinline__ float sigm(float x) { return 1.0f / (1.0f + __expf(-x)); }
__device__ __forceinline__ float ftanh(float x) {
  float ax = fabsf(x);
  float e = __expf(2.0f * ax);
  float tv = 1.0f - 2.0f / (e + 1.0f);
  return copysignf(tv, x);
}
__device__ __forceinline__ float bf2f(unsigned u) { return __uint_as_float(u << 16); }
__device__ __forceinline__ bf16x8 ldfrag(const __hip_bfloat16* p) {
  return *reinterpret_cast<const bf16x8*>(p);
}
__device__ __forceinline__ u64 ld_u64_sys(const void* p) {
  return __hip_atomic_load((u64*)p, __ATOMIC_RELAXED, __HIP_MEMORY_SCOPE_AGENT);
}
__device__ __forceinline__ bf16x8 ldfrag_sys(const __hip_bfloat16* p) {
  union { u64 u[2]; bf16x8 v; } r;
  r.u[0] = ld_u64_sys(p);
  r.u[1] = ld_u64_sys((const char*)p + 8);
  return r.v;
}
__device__ __forceinline__ void st_u32_sys(void* p, unsigned v) {
  __hip_atomic_store((unsigned*)p, v, __ATOMIC_RELAXED, __HIP_MEMORY_SCOPE_AGENT);
}
__device__ __forceinline__ unsigned pack2bf(float a, float b) {
  __hip_bfloat16 ha = __float2bfloat16(a), hb = __float2bfloat16(b);
  unsigned short ua = *(unsigned short*)&ha, ub = *(unsigned short*)&hb;
  return (unsigned)ua | ((unsigned)ub << 16);
}

// ------------------------------------------------------------- prep kernels
__global__ __launch_bounds__(256) void k_prep_w1(const float* __restrict__ Wih1,
                                                 const float* __restrict__ Whh1,
                                                 const float* __restrict__ bih1,
                                                 const float* __restrict__ bhh1,
                                                 __hip_bfloat16* __restrict__ W1bf,
                                                 float* __restrict__ bsum1) {
  int r = blockIdx.x;
  const float* wi = Wih1 + (size_t)r * 640;
  const float* wh = Whh1 + (size_t)r * 1024;
  for (int k = threadIdx.x; k < K1; k += 256)
    W1bf[(size_t)r * K1 + k] = __float2bfloat16(k < 640 ? wi[k] : wh[k - 640]);
  if (threadIdx.x == 0) bsum1[r] = bih1[r] + bhh1[r];
}

__global__ __launch_bounds__(256) void k_prep_w2t(const float* __restrict__ Wih2,
                                                  const float* __restrict__ Whh2,
                                                  const float* __restrict__ bih2,
                                                  const float* __restrict__ bhh2,
                                                  __hip_bfloat16* __restrict__ W2T,
                                                  float* __restrict__ bsum2) {
  int r = blockIdx.x;  // 512 rows
  for (int idx = threadIdx.x; idx < K2; idx += 256) {
    int kb = idx >> 3, j = idx & 7;
    float v = (idx < 1024) ? Wih2[(size_t)r * 1024 + idx]
                           : Whh2[(size_t)r * 128 + idx - 1024];
    W2T[((size_t)(kb * 512 + r)) * 8 + j] = __float2bfloat16(v);
  }
  if (threadIdx.x == 0) bsum2[r] = bih2[r] + bhh2[r];
}

__global__ __launch_bounds__(256) void k_prep_wout(const float* __restrict__ Wout,
                                                   __hip_bfloat16* __restrict__ Woutbf) {
  int r0 = blockIdx.x * 16;
  for (int idx = threadIdx.x; idx < 16 * 256; idx += 256) {
    int r = r0 + (idx >> 8), k = idx & 255;
    Woutbf[(size_t)r * 256 + k] = __float2bfloat16(Wout[(size_t)r * 256 + k]);
  }
}

__global__ __launch_bounds__(256) void k_gather(const int* __restrict__ text,
                                                const float* __restrict__ emb,
                                                __hip_bfloat16* __restrict__ xembbf) {
  int t = blockIdx.x;
  __shared__ int tok[NB];
  if (threadIdx.x < NB) tok[threadIdx.x] = text[threadIdx.x * TDEC + t];
  __syncthreads();
  for (int idx = threadIdx.x; idx < NB * EMBD; idx += 256) {
    int n = idx >> 9, k = idx & 511;
    xembbf[((size_t)t * NB + n) * EMBD + k] =
        __float2bfloat16(emb[(size_t)tok[n] * EMBD + k]);
  }
}

__global__ __launch_bounds__(256) void k_prep_kv(const float* __restrict__ key,
                                                 const float* __restrict__ value,
                                                 __hip_bfloat16* __restrict__ keybf,
                                                 __hip_bfloat16* __restrict__ valbf) {
  int gsz = gridDim.x * 256;
  for (size_t i = blockIdx.x * 256 + threadIdx.x; i < (size_t)NB * TENC * KSZ; i += gsz) {
    keybf[i] = __float2bfloat16(key[i]);
    valbf[i] = __float2bfloat16(value[i]);
  }
}

// --------------------------------------------- grid barrier (relaxed atomics)
__device__ __forceinline__ void gbar(unsigned* cnt, unsigned* rel, int ep, int wg) {
  asm volatile("s_waitcnt vmcnt(0)" ::: "memory");
  __syncthreads();
  int tid = threadIdx.x;
  if (tid == 0)
    __hip_atomic_fetch_add(&cnt[(wg & 7) << 4], 1u, __ATOMIC_RELAXED,
                           __HIP_MEMORY_SCOPE_AGENT);
  if (wg == 0 && tid < 64) {
    unsigned need = (unsigned)ep * 8u;
    for (;;) {
      unsigned v = __hip_atomic_load(&cnt[(tid & 7) << 4], __ATOMIC_RELAXED,
                                     __HIP_MEMORY_SCOPE_AGENT);
      if (__all((int)(v >= need))) break;
      __builtin_amdgcn_s_sleep(1);
    }
    if (tid == 0)
      __hip_atomic_store(rel, (unsigned)ep, __ATOMIC_RELAXED, __HIP_MEMORY_SCOPE_AGENT);
  }
  if (tid == 0) {
    while (__hip_atomic_load(rel, __ATOMIC_RELAXED, __HIP_MEMORY_SCOPE_AGENT) <
           (unsigned)ep)
      __builtin_amdgcn_s_sleep(1);
  }
  __syncthreads();
}

// ------------------------------------------------------- persistent kernel
struct LA {
  const float* key;
  const float* value;
  const int* slen;
  const __hip_bfloat16* keybf;
  const __hip_bfloat16* valbf;
  int kv;
  const __hip_bfloat16* W1bf;
  const __hip_bfloat16* W2T;
  const __hip_bfloat16* xembbf;
  const float* bsum1;
  const float* bsum2;
  __hip_bfloat16* h1bf;   // [2][64][1024]
  __hip_bfloat16* ctxbf;  // [64][128]
  __hip_bfloat16* h2cbf;  // [12800][256]
  unsigned* bar_cnt;
  unsigned* bar_rel;
};

__global__ __launch_bounds__(NTH) void k_loop(LA a) {
  const int wg = blockIdx.x, tid = threadIdx.x;
  const int lane = tid & 63, wid = tid >> 6;
  const int ln15 = lane & 15, lg = lane >> 4, ko = lg * 8;
  const int bg = wid & 3, kh = wid >> 2;
  const int d0 = wg * 16;

  __shared__ float bs1l[16][4];
  __shared__ float h2st[2][128];
  __shared__ float c2st[2][128];
  __shared__ float bs2l[4][128];
  __shared__ __align__(16) char smem[33792];
  float* part = (float*)smem;            // B: [4][4][64][4] f32 (16KB)
  float* gl   = (float*)(smem + 16384);  // B: [4][4][16][16] f32 (16KB)
  float* h1s  = (float*)smem;            // CA: [2][1024] f32 (8KB)
  float* g2   = (float*)(smem + 8192);   // CA: [2][512] f32 (4KB)
  float* e_l  = (float*)(smem + 12288);  // CA: [2][512] f32 (4KB)
  float* red  = (float*)(smem + 16384);  // CA: [2][256] f32 (2KB)
  float* ctxp = (float*)(smem + 18432);  // CA: [2][2][128] f32 (2KB)

  float creg0 = 0.f, creg1 = 0.f;  // persistent c1 (2 dims/thread)

  // W1 row pointers for the 4 B-tiles (constant over t)
  const __hip_bfloat16 *wb0, *wb1, *wb2, *wb3;
  {
    int g = ln15 & 3, s = ln15 >> 2;
    wb0 = a.W1bf + (size_t)(g * 1024 + d0 + 0 + s) * K1;
    wb1 = a.W1bf + (size_t)(g * 1024 + d0 + 4 + s) * K1;
    wb2 = a.W1bf + (size_t)(g * 1024 + d0 + 8 + s) * K1;
    wb3 = a.W1bf + (size_t)(g * 1024 + d0 + 12 + s) * K1;
  }
  const int nA = bg * 16 + ln15;  // A-operand batch row for this lane

  int len0 = 0, len1 = 0;
  if (wg < 32) { len0 = a.slen[wg * 2]; len1 = a.slen[wg * 2 + 1]; }

  // -------------------------------- prologue: biases to LDS, ctx0 = mean(V)
  if (tid < 64) bs1l[tid >> 2][tid & 3] = a.bsum1[(tid & 3) * 1024 + d0 + (tid >> 2)];
  if (wg < 32) {
    bs2l[tid >> 7][tid & 127] = a.bsum2[tid];
    if (tid < 256) { h2st[tid >> 7][tid & 127] = 0.f; c2st[tid >> 7][tid & 127] = 0.f; }
    __syncthreads();
    {
      int l = tid & 255, nl = tid >> 8;
      int n = wg * 2 + nl, len = nl ? len1 : len0;
      int v = l & 127, ph = l >> 7;
      float acc = 0.f;
      if (a.kv) {
        const unsigned short* vb = (const unsigned short*)a.valbf;
        for (int p = ph; p < len; p += 2)
          acc += bf2f(vb[((size_t)n * TENC + p) * VSZ + v]);
      } else {
        for (int p = ph; p < len; p += 2)
          acc += a.value[((size_t)n * TENC + p) * VSZ + v];
      }
      ctxp[(nl * 2 + ph) * 128 + v] = acc;
    }
    __syncthreads();
    if (tid < 128) {
      int nl = tid >> 6, vp = tid & 63, n = wg * 2 + nl;
      float invl = 1.f / (float)(nl ? len1 : len0);
      float c0 = (ctxp[(nl * 2) * 128 + 2 * vp] + ctxp[(nl * 2 + 1) * 128 + 2 * vp]) * invl;
      float c1 = (ctxp[(nl * 2) * 128 + 2 * vp + 1] + ctxp[(nl * 2 + 1) * 128 + 2 * vp + 1]) * invl;
      unsigned pk = pack2bf(c0, c1);
      st_u32_sys(a.ctxbf + n * 128 + 2 * vp, pk);
      *(unsigned*)&a.h2cbf[((size_t)0 * NB + n) * 256 + 128 + 2 * vp] = pk;
    }
  }
  int ep = 0;
  gbar(a.bar_cnt, a.bar_rel, ++ep, wg);

  // -------------------------------- main loop
  for (int t = 0; t < TDEC; ++t) {
    const int cur = t & 1;
    const __hip_bfloat16* h1c = a.h1bf + (size_t)cur * 65536;
    __hip_bfloat16* h1n = a.h1bf + (size_t)(cur ^ 1) * 65536;

    // ---------- phase B: LSTM1 (all 64 WGs; WG owns 16 h1 dims)
    {
      const __hip_bfloat16* ax = a.xembbf + ((size_t)t * NB + nA) * EMBD;
      const __hip_bfloat16* ac = a.ctxbf + nA * 128;
      const __hip_bfloat16* ah = h1c + nA * 1024;
      f32x4 q0 = {0, 0, 0, 0}, q1 = {0, 0, 0, 0}, q2 = {0, 0, 0, 0}, q3 = {0, 0, 0, 0};
      if (kh == 0) {
        #pragma unroll
        for (int s = 0; s < 16; ++s) {
          bf16x8 av = ldfrag(ax + s * 32 + ko);
          int o = s * 32 + ko;
          q0 = MFMA16(av, ldfrag(wb0 + o), q0);
          q1 = MFMA16(av, ldfrag(wb1 + o), q1);
          q2 = MFMA16(av, ldfrag(wb2 + o), q2);
          q3 = MFMA16(av, ldfrag(wb3 + o), q3);
        }
        #pragma unroll
        for (int s = 0; s < 4; ++s) {
          bf16x8 av = ldfrag_sys(ac + s * 32 + ko);
          int o = 512 + s * 32 + ko;
          q0 = MFMA16(av, ldfrag(wb0 + o), q0);
          q1 = MFMA16(av, ldfrag(wb1 + o), q1);
          q2 = MFMA16(av, ldfrag(wb2 + o), q2);
          q3 = MFMA16(av, ldfrag(wb3 + o), q3);
        }
        #pragma unroll
        for (int s = 0; s < 6; ++s) {
          bf16x8 av = ldfrag_sys(ah + s * 32 + ko);
          int o = 640 + s * 32 + ko;
          q0 = MFMA16(av, ldfrag(wb0 + o), q0);
          q1 = MFMA16(av, ldfrag(wb1 + o), q1);
          q2 = MFMA16(av, ldfrag(wb2 + o), q2);
          q3 = MFMA16(av, ldfrag(wb3 + o), q3);
        }
      } else {
        #pragma unroll
        for (int s = 0; s < 26; ++s) {
          bf16x8 av = ldfrag_sys(ah + 192 + s * 32 + ko);
          int o = 832 + s * 32 + ko;
          q0 = MFMA16(av, ldfrag(wb0 + o), q0);
          q1 = MFMA16(av, ldfrag(wb1 + o), q1);
          q2 = MFMA16(av, ldfrag(wb2 + o), q2);
          q3 = MFMA16(av, ldfrag(wb3 + o), q3);
        }
      }
      if (kh == 1) {
        *(f32x4*)&part[(((bg * 4 + 0) * 64) + lane) * 4] = q0;
        *(f32x4*)&part[(((bg * 4 + 1) * 64) + lane) * 4] = q1;
        *(f32x4*)&part[(((bg * 4 + 2) * 64) + lane) * 4] = q2;
        *(f32x4*)&part[(((bg * 4 + 3) * 64) + lane) * 4] = q3;
      }
      __syncthreads();
      if (kh == 0) {
        q0 += *(f32x4*)&part[(((bg * 4 + 0) * 64) + lane) * 4];
        q1 += *(f32x4*)&part[(((bg * 4 + 1) * 64) + lane) * 4];
        q2 += *(f32x4*)&part[(((bg * 4 + 2) * 64) + lane) * 4];
        q3 += *(f32x4*)&part[(((bg * 4 + 3) * 64) + lane) * 4];
        #pragma unroll
        for (int r = 0; r < 4; ++r) {
          gl[((bg * 4 + 0) * 16 + (lg * 4 + r)) * 16 + ln15] = q0[r];
          gl[((bg * 4 + 1) * 16 + (lg * 4 + r)) * 16 + ln15] = q1[r];
          gl[((bg * 4 + 2) * 16 + (lg * 4 + r)) * 16 + ln15] = q2[r];
          gl[((bg * 4 + 3) * 16 + (lg * 4 + r)) * 16 + ln15] = q3[r];
        }
      }
      __syncthreads();
      {  // tail: thread owns (n, dim-pair)
        int n = tid >> 3, dp = tid & 7;
        int bgg = n >> 4, ii = n & 15;
        int t4 = dp >> 1, off = (dp & 1) * 8;
        float* gp = &gl[((bgg * 4 + t4) * 16 + ii) * 16 + off];
        float4 gA = *(float4*)gp;
        float4 gB = *(float4*)(gp + 4);
        int dA = dp * 2, dB = dp * 2 + 1;
        float I = sigm(gA.x + bs1l[dA][0]);
        float F = sigm(gA.y + bs1l[dA][1]);
        float G = ftanh(gA.z + bs1l[dA][2]);
        float O = sigm(gA.w + bs1l[dA][3]);
        float cv = F * creg0 + I * G;
        creg0 = cv;
        float hA = O * ftanh(cv);
        I = sigm(gB.x + bs1l[dB][0]);
        F = sigm(gB.y + bs1l[dB][1]);
        G = ftanh(gB.z + bs1l[dB][2]);
        O = sigm(gB.w + bs1l[dB][3]);
        cv = F * creg1 + I * G;
        creg1 = cv;
        float hB = O * ftanh(cv);
        st_u32_sys(h1n + n * 1024 + d0 + dA, pack2bf(hA, hB));
      }
    }
    gbar(a.bar_cnt, a.bar_rel, ++ep, wg);

    // ---------- phase CA: LSTM2 + attention (WGs 0..31, 2 batch rows each)
    if (wg < 32) {
      {  // stage h1 rows (2KB each) -> LDS fp32
        int row = tid >> 8, i4 = (tid & 255) << 2;
        u64 u = ld_u64_sys(h1n + (wg * 2 + row) * 1024 + i4);
        h1s[row * 1024 + i4 + 0] = bf2f((unsigned)(u & 0xffffu));
        h1s[row * 1024 + i4 + 1] = bf2f((unsigned)((u >> 16) & 0xffffu));
        h1s[row * 1024 + i4 + 2] = bf2f((unsigned)((u >> 32) & 0xffffu));
        h1s[row * 1024 + i4 + 3] = bf2f((unsigned)(u >> 48));
      }
      __syncthreads();
      {  // lstm2: thread owns gate-row r for both n
        int r = tid;
        float a0 = 0.f, a1 = 0.f;
        #pragma unroll 8
        for (int kb = 0; kb < 144; ++kb) {
          uint4 wv = *(const uint4*)(a.W2T + (size_t)(kb * 512 + r) * 8);
          const float* iA = (kb < 128) ? &h1s[kb * 8] : &h2st[0][(kb - 128) * 8];
          const float* iB = (kb < 128) ? &h1s[1024 + kb * 8] : &h2st[1][(kb - 128) * 8];
          float w0 = bf2f(wv.x & 0xffffu), w1 = bf2f(wv.x >> 16);
          float w2 = bf2f(wv.y & 0xffffu), w3 = bf2f(wv.y >> 16);
          float w4 = bf2f(wv.z & 0xffffu), w5 = bf2f(wv.z >> 16);
          float w6 = bf2f(wv.w & 0xffffu), w7 = bf2f(wv.w >> 16);
          a0 += w0 * iA[0] + w1 * iA[1] + w2 * iA[2] + w3 * iA[3]
              + w4 * iA[4] + w5 * iA[5] + w6 * iA[6] + w7 * iA[7];
          a1 += w0 * iB[0] + w1 * iB[1] + w2 * iB[2] + w3 * iB[3]
              + w4 * iB[4] + w5 * iB[5] + w6 * iB[6] + w7 * iB[7];
        }
        g2[r] = a0;
        g2[512 + r] = a1;
      }
      __syncthreads();
      if (tid < 256) {  // combine gates, update c2/h2 (LDS state)
        int nl = tid >> 7, dd = tid & 127;
        float* gg = &g2[nl * 512];
        float I = sigm(gg[dd] + bs2l[0][dd]);
        float F = sigm(gg[128 + dd] + bs2l[1][dd]);
        float G = ftanh(gg[256 + dd] + bs2l[2][dd]);
        float O = sigm(gg[384 + dd] + bs2l[3][dd]);
        float cv = F * c2st[nl][dd] + I * G;
        c2st[nl][dd] = cv;
        float h = O * ftanh(cv);
        h2st[nl][dd] = h;
        a.h2cbf[((size_t)t * NB + wg * 2 + nl) * 256 + dd] = __float2bfloat16(h);
      }
      __syncthreads();
      if (t < TDEC - 1) {  // attention for step t+1 with fresh h2
        int l = tid & 255, nl = tid >> 8;
        int n = wg * 2 + nl, len = nl ? len1 : len0;
        int pA = l, pB = l + 256;
        auto edot = [&](int p) -> float {
          float s = 0.f;
          if (a.kv) {
            const uint4* kr = (const uint4*)(a.keybf + ((size_t)n * TENC + p) * KSZ);
            #pragma unroll
            for (int kk = 0; kk < 16; ++kk) {
              uint4 u = kr[kk];
              const float* hh = &h2st[nl][kk * 8];
              s += bf2f(u.x & 0xffffu) * hh[0] + bf2f(u.x >> 16) * hh[1]
                 + bf2f(u.y & 0xffffu) * hh[2] + bf2f(u.y >> 16) * hh[3]
                 + bf2f(u.z & 0xffffu) * hh[4] + bf2f(u.z >> 16) * hh[5]
                 + bf2f(u.w & 0xffffu) * hh[6] + bf2f(u.w >> 16) * hh[7];
            }
          } else {
            const float4* kr = (const float4*)(a.key + ((size_t)n * TENC + p) * KSZ);
            #pragma unroll 8
            for (int kk = 0; kk < 32; ++kk) {
              float4 u = kr[kk];
              const float* hh = &h2st[nl][kk * 4];
              s += u.x * hh[0] + u.y * hh[1] + u.z * hh[2] + u.w * hh[3];
            }
          }
          return s;
        };
        float eA = -1e9f, eB = -1e9f;
        if (pA < len) eA = edot(pA);
        if (pB < 500 && pB < len) eB = edot(pB);
        red[nl * 256 + l] = fmaxf(eA, eB);
        __syncthreads();
        for (int s2 = 128; s2 > 0; s2 >>= 1) {
          if (l < s2) {
            int b = nl * 256 + l;
            red[b] = fmaxf(red[b], red[b + s2]);
          }
          __syncthreads();
        }
        float m = red[nl * 256];
        __syncthreads();
        float xA = (pA < len) ? __expf(eA - m) : 0.f;
        float xB = (pB < len && pB < 500) ? __expf(eB - m) : 0.f;
        e_l[nl * 512 + pA] = xA;
        e_l[nl * 512 + pB] = xB;
        red[nl * 256 + l] = xA + xB;
        __syncthreads();
        for (int s2 = 128; s2 > 0; s2 >>= 1) {
          if (l < s2) {
            int b = nl * 256 + l;
            red[b] += red[b + s2];
          }
          __syncthreads();
        }
        float inv = 1.f / red[nl * 256];
        {
          int v = l & 127, ph = l >> 7;
          float accv = 0.f;
          if (a.kv) {
            const unsigned short* vb = (const unsigned short*)a.valbf;
            for (int p = ph; p < len; p += 2)
              accv += e_l[nl * 512 + p] * bf2f(vb[((size_t)n * TENC + p) * VSZ + v]);
          } else {
            for (int p = ph; p < len; p += 2)
              accv += e_l[nl * 512 + p] * a.value[((size_t)n * TENC + p) * VSZ + v];
          }
          ctxp[(nl * 2 + ph) * 128 + v] = accv * inv;
        }
        __syncthreads();
        if (tid < 128) {
          int nl2 = tid >> 6, vp = tid & 63, n2 = wg * 2 + nl2;
          float c0 = ctxp[(nl2 * 2) * 128 + 2 * vp] + ctxp[(nl2 * 2 + 1) * 128 + 2 * vp];
          float c1v = ctxp[(nl2 * 2) * 128 + 2 * vp + 1] + ctxp[(nl2 * 2 + 1) * 128 + 2 * vp + 1];
          unsigned pk = pack2bf(c0, c1v);
          st_u32_sys(a.ctxbf + n2 * 128 + 2 * vp, pk);
          *(unsigned*)&a.h2cbf[((size_t)(t + 1) * NB + n2) * 256 + 128 + 2 * vp] = pk;
        }
      }
    }
    gbar(a.bar_cnt, a.bar_rel, ++ep, wg);
  }
}

// ------------------------------------------------------ output projection
__global__ __launch_bounds__(256) void k_out(const __hip_bfloat16* __restrict__ h2cbf,
                                             const __hip_bfloat16* __restrict__ Woutbf,
                                             const float* __restrict__ bout,
                                             float* __restrict__ out) {
  int tid = threadIdx.x;
  int w = tid >> 6, lane = tid & 63;
  int ln15 = lane & 15, lg = lane >> 4, ko = lg * 8;
  int c0 = blockIdx.x * 64, m0 = blockIdx.y * 64;
  const __hip_bfloat16* ap = h2cbf + (size_t)(m0 + w * 16 + ln15) * 256;
  bf16x8 afr[8];
  #pragma unroll
  for (int kk = 0; kk < 8; ++kk) afr[kk] = ldfrag(ap + kk * 32 + ko);
  union U16 { uint4 u; bf16x8 v; };
  #pragma unroll
  for (int s = 0; s < 4; ++s) {
    int r = c0 + s * 16 + ln15;
    const __hip_bfloat16* bp = Woutbf + (size_t)r * 256;
    bool ok = r < VOCAB;
    f32x4 acc = {0.f, 0.f, 0.f, 0.f};
    #pragma unroll
    for (int kk = 0; kk < 8; ++kk) {
      U16 bv;
      bv.u = make_uint4(0, 0, 0, 0);
      if (ok) bv.v = ldfrag(bp + kk * 32 + ko);
      acc = MFMA16(afr[kk], bv.v, acc);
    }
    int c = c0 + s * 16 + ln15;
    if (c < VOCAB) {
      float bb = bout[c];
      #pragma unroll
      for (int reg = 0; reg < 4; ++reg) {
        int m = m0 + w * 16 + 4 * lg + reg;
        int n = m & 63, tt = m >> 6;
        out[((size_t)n * TDEC + tt) * VOCAB + c] = acc[reg] + bb;
      }
    }
  }
}

// ---------------------------------------------------------------------------
extern "C" void kernel_launch(void* const* d_in, const int* in_sizes, int n_in,
                              void* d_out, int out_size, void* d_ws, size_t ws_size,
                              hipStream_t stream) {
  (void)in_sizes; (void)n_in; (void)out_size;
  const float* key   = (const float*)d_in[0];
  const float* value = (const float*)d_in[1];
  const int*   slen  = (const int*)d_in[2];
  const int*   text  = (const int*)d_in[3];
  const float* emb   = (const float*)d_in[4];
  const float* Wih1  = (const float*)d_in[5];
  const float* Whh1  = (const float*)d_in[6];
  const float* bih1  = (const float*)d_in[7];
  const float* bhh1  = (const float*)d_in[8];
  const float* Wih2  = (const float*)d_in[9];
  const float* Whh2  = (const float*)d_in[10];
  const float* bih2  = (const float*)d_in[11];
  const float* bhh2  = (const float*)d_in[12];
  const float* Wout  = (const float*)d_in[13];
  const float* bout  = (const float*)d_in[14];
  float* out = (float*)d_out;
  char* ws = (char*)d_ws;

  __hip_bfloat16* W1bf   = (__hip_bfloat16*)(ws + OFF_W1);
  __hip_bfloat16* W2T    = (__hip_bfloat16*)(ws + OFF_W2T);
  __hip_bfloat16* Woutbf = (__hip_bfloat16*)(ws + OFF_WOUT);
  __hip_bfloat16* xembbf = (__hip_bfloat16*)(ws + OFF_XEMB);
  __hip_bfloat16* h2cbf  = (__hip_bfloat16*)(ws + OFF_H2C);
  float* bsum1 = (float*)(ws + OFF_BS1);
  float* bsum2 = (float*)(ws + OFF_BS2);
  int kv = (ws_size >= KV_END) ? 1 : 0;
  __hip_bfloat16* keybf = (__hip_bfloat16*)(ws + OFF_KEYBF);
  __hip_bfloat16* valbf = (__hip_bfloat16*)(ws + OFF_VALBF);

  hipMemsetAsync(d_ws, 0, 266240, stream);  // barrier flags + h1 buffers
  k_prep_w1<<<4096, 256, 0, stream>>>(Wih1, Whh1, bih1, bhh1, W1bf, bsum1);
  k_prep_w2t<<<512, 256, 0, stream>>>(Wih2, Whh2, bih2, bhh2, W2T, bsum2);
  k_prep_wout<<<625, 256, 0, stream>>>(Wout, Woutbf);
  k_gather<<<TDEC, 256, 0, stream>>>(text, emb, xembbf);
  if (kv) k_prep_kv<<<2048, 256, 0, stream>>>(key, value, keybf, valbf);

  LA la;
  la.key = key; la.value = value; la.slen = slen;
  la.keybf = keybf; la.valbf = valbf; la.kv = kv;
  la.W1bf = W1bf; la.W2T = W2T; la.xembbf = xembbf;
  la.bsum1 = bsum1; la.bsum2 = bsum2;
  la.h1bf = (__hip_bfloat16*)(ws + OFF_H1);
  la.ctxbf = (__hip_bfloat16*)(ws + OFF_CTX);
  la.h2cbf = h2cbf;
  la.bar_cnt = (unsigned*)(ws + OFF_BAR);
  la.bar_rel = (unsigned*)(ws + OFF_BAR + 1024);

  void* args[] = {&la};
  hipLaunchCooperativeKernel((void*)k_loop, dim3(NWG), dim3(NTH), args, 0, stream);

  k_out<<<dim3(157, 200), 256, 0, stream>>>(h2cbf, Woutbf, bout, out);
}

// Round 4
// 13966.998 us; speedup vs baseline: 3.8137x; 2.0941x over previous
//
#include <hip/hip_runtime.h>
#include <hip/hip_bf16.h>
#include <math.h>

// ---------------------------------------------------------------------------
// Round 4: stream-ordered again (kernel boundaries = cross-XCD coherence; all
// loads normally cached), 2 kernels/step: k_lstm1 (bf16 MFMA, 256 WGs) and
// k_ca (fused LSTM2 + attention, 64 WGs, one batch row each). bf16 weights,
// bf16 KV. Deferred output projection k_out (bf16 MFMA) at the end.
// ---------------------------------------------------------------------------

#define NB    64
#define TENC  500
#define TDEC  200
#define EMBD  512
#define HID   1024
#define KSZ   128
#define VSZ   128
#define VOCAB 10000
#define K1    1664
#define K2    1152

typedef __bf16 bf16x8 __attribute__((ext_vector_type(8)));
typedef float f32x4 __attribute__((ext_vector_type(4)));
#define MFMA16(a, b, c) __builtin_amdgcn_mfma_f32_16x16x32_bf16((a), (b), (c), 0, 0, 0)

// ws layout (bytes)
constexpr size_t OFF_H1    = 0;          // bf16 [2][64][1024] = 262144
constexpr size_t OFF_H2G   = 262144;     // bf16 [64][128]     = 16384
constexpr size_t OFF_C1    = 278528;     // f32  [64][1024]    = 262144
constexpr size_t OFF_C2    = 540672;     // f32  [64][128]     = 32768
constexpr size_t ZERO_END  = 573440;
constexpr size_t OFF_CTX   = 573440;     // bf16 [64][128]     = 16384
constexpr size_t OFF_BS1   = 589824;     // f32 [4096]
constexpr size_t OFF_BS2   = 606208;     // f32 [512]
constexpr size_t OFF_W2T   = 608256;     // bf16 [144][512][8] = 1179648
constexpr size_t OFF_W1    = 1787904;    // bf16 [4096][1664]  = 13631488
constexpr size_t OFF_WOUT  = 15419392;   // bf16 [10000][256]  = 5120000
constexpr size_t OFF_XEMB  = 20539392;   // bf16 [200][64][512]= 13107200
constexpr size_t OFF_H2C   = 33646592;   // bf16 [12800][256]  = 6553600
constexpr size_t BASE_END  = 40200192;
constexpr size_t OFF_KEYBF = 40200192;   // bf16 [64][500][128] = 8192000
constexpr size_t OFF_VALBF = 48392192;   // bf16 [64][500][128] = 8192000
constexpr size_t KV_END    = 56584192;

__device__ __forceinline__ float sigm(float x) { return 1.0f / (1.0f + __expf(-x)); }
__device__ __forceinline__ float ftanh(float x) {
  float ax = fabsf(x);
  float e = __expf(2.0f * ax);
  float tv = 1.0f - 2.0f / (e + 1.0f);
  return copysignf(tv, x);
}
__device__ __forceinline__ float bf2f(unsigned u) { return __uint_as_float(u << 16); }
__device__ __forceinline__ bf16x8 ldfrag(const __hip_bfloat16* p) {
  return *reinterpret_cast<const bf16x8*>(p);
}

// ------------------------------------------------------------- prep kernels
__global__ __launch_bounds__(256) void k_prep_w1(const float* __restrict__ Wih1,
                                                 const float* __restrict__ Whh1,
                                                 const float* __restrict__ bih1,
                                                 const float* __restrict__ bhh1,
                                                 __hip_bfloat16* __restrict__ W1bf,
                                                 float* __restrict__ bsum1) {
  int r = blockIdx.x;
  const float* wi = Wih1 + (size_t)r * 640;
  const float* wh = Whh1 + (size_t)r * 1024;
  for (int k = threadIdx.x; k < K1; k += 256)
    W1bf[(size_t)r * K1 + k] = __float2bfloat16(k < 640 ? wi[k] : wh[k - 640]);
  if (threadIdx.x == 0) bsum1[r] = bih1[r] + bhh1[r];
}

__global__ __launch_bounds__(256) void k_prep_w2t(const float* __restrict__ Wih2,
                                                  const float* __restrict__ Whh2,
                                                  const float* __restrict__ bih2,
                                                  const float* __restrict__ bhh2,
                                                  __hip_bfloat16* __restrict__ W2T,
                                                  float* __restrict__ bsum2) {
  int r = blockIdx.x;  // 512 rows
  for (int idx = threadIdx.x; idx < K2; idx += 256) {
    int kb = idx >> 3, j = idx & 7;
    float v = (idx < 1024) ? Wih2[(size_t)r * 1024 + idx]
                           : Whh2[(size_t)r * 128 + idx - 1024];
    W2T[((size_t)(kb * 512 + r)) * 8 + j] = __float2bfloat16(v);
  }
  if (threadIdx.x == 0) bsum2[r] = bih2[r] + bhh2[r];
}

__global__ __launch_bounds__(256) void k_prep_wout(const float* __restrict__ Wout,
                                                   __hip_bfloat16* __restrict__ Woutbf) {
  int r0 = blockIdx.x * 16;
  for (int idx = threadIdx.x; idx < 16 * 256; idx += 256) {
    int r = r0 + (idx >> 8), k = idx & 255;
    Woutbf[(size_t)r * 256 + k] = __float2bfloat16(Wout[(size_t)r * 256 + k]);
  }
}

__global__ __launch_bounds__(256) void k_gather(const int* __restrict__ text,
                                                const float* __restrict__ emb,
                                                __hip_bfloat16* __restrict__ xembbf) {
  int t = blockIdx.x;
  __shared__ int tok[NB];
  if (threadIdx.x < NB) tok[threadIdx.x] = text[threadIdx.x * TDEC + t];
  __syncthreads();
  for (int idx = threadIdx.x; idx < NB * EMBD; idx += 256) {
    int n = idx >> 9, k = idx & 511;
    xembbf[((size_t)t * NB + n) * EMBD + k] =
        __float2bfloat16(emb[(size_t)tok[n] * EMBD + k]);
  }
}

__global__ __launch_bounds__(256) void k_prep_kv(const float* __restrict__ key,
                                                 const float* __restrict__ value,
                                                 __hip_bfloat16* __restrict__ keybf,
                                                 __hip_bfloat16* __restrict__ valbf) {
  int gsz = gridDim.x * 256;
  for (size_t i = blockIdx.x * 256 + threadIdx.x; i < (size_t)NB * TENC * KSZ; i += gsz) {
    keybf[i] = __float2bfloat16(key[i]);
    valbf[i] = __float2bfloat16(value[i]);
  }
}

__global__ __launch_bounds__(256) void k_ctx0(const float* __restrict__ value,
                                              const __hip_bfloat16* __restrict__ valbf,
                                              int kv, const int* __restrict__ slen,
                                              __hip_bfloat16* __restrict__ ctxbf,
                                              __hip_bfloat16* __restrict__ h2cbf) {
  int n = blockIdx.x, tid = threadIdx.x;
  __shared__ float ctxp[2][128];
  int len = slen[n];
  int v = tid & 127, ph = tid >> 7;
  float acc = 0.f;
  if (kv) {
    const unsigned short* vb = (const unsigned short*)valbf;
    for (int p = ph; p < len; p += 2) acc += bf2f(vb[((size_t)n * TENC + p) * VSZ + v]);
  } else {
    for (int p = ph; p < len; p += 2) acc += value[((size_t)n * TENC + p) * VSZ + v];
  }
  ctxp[ph][v] = acc;
  __syncthreads();
  if (tid < 128) {
    float c = (ctxp[0][tid] + ctxp[1][tid]) / (float)len;
    __hip_bfloat16 cb = __float2bfloat16(c);
    ctxbf[n * 128 + tid] = cb;
    h2cbf[(size_t)n * 256 + 128 + tid] = cb;
  }
}

// ---------------------------------------------------------------- k_lstm1
// grid 256, block 512 (8 waves). WG owns 4 h-dims (16 gate rows).
// waves: bg=wid&3 -> batch group of 16, kh=wid>>2 -> K half (832 each).
// B-frag lane j=ln15 -> gate row (j&3)*1024 + d0 + (j>>2).
__global__ __launch_bounds__(512, 2) void k_lstm1(
    const __hip_bfloat16* __restrict__ xembbf, const __hip_bfloat16* __restrict__ ctxbf,
    const __hip_bfloat16* __restrict__ h1cur, __hip_bfloat16* __restrict__ h1nxt,
    float* __restrict__ c1, const __hip_bfloat16* __restrict__ W1bf,
    const float* __restrict__ bsum1, int t) {
  __shared__ float part[4][64][4];
  __shared__ float gl[4][16][16];
  int tid = threadIdx.x, lane = tid & 63, wid = tid >> 6;
  int ln15 = lane & 15, lg = lane >> 4, ko = lg * 8;
  int bg = wid & 3, kh = wid >> 2;
  int d0 = blockIdx.x * 4;
  const __hip_bfloat16* wp = W1bf + (size_t)((ln15 & 3) * 1024 + d0 + (ln15 >> 2)) * K1;
  int nA = bg * 16 + ln15;
  const __hip_bfloat16* ax = xembbf + ((size_t)t * NB + nA) * EMBD;
  const __hip_bfloat16* ac = ctxbf + nA * 128;
  const __hip_bfloat16* ah = h1cur + nA * 1024;
  f32x4 q = {0.f, 0.f, 0.f, 0.f};
  if (kh == 0) {
    #pragma unroll
    for (int s = 0; s < 16; ++s) q = MFMA16(ldfrag(ax + s * 32 + ko), ldfrag(wp + s * 32 + ko), q);
    #pragma unroll
    for (int s = 0; s < 4; ++s) q = MFMA16(ldfrag(ac + s * 32 + ko), ldfrag(wp + 512 + s * 32 + ko), q);
    #pragma unroll
    for (int s = 0; s < 6; ++s) q = MFMA16(ldfrag(ah + s * 32 + ko), ldfrag(wp + 640 + s * 32 + ko), q);
  } else {
    #pragma unroll
    for (int s = 0; s < 26; ++s) q = MFMA16(ldfrag(ah + 192 + s * 32 + ko), ldfrag(wp + 832 + s * 32 + ko), q);
  }
  if (kh == 1) *(f32x4*)&part[bg][lane][0] = q;
  __syncthreads();
  if (kh == 0) {
    q += *(f32x4*)&part[bg][lane][0];
    #pragma unroll
    for (int r = 0; r < 4; ++r) gl[bg][lg * 4 + r][ln15] = q[r];
  }
  __syncthreads();
  if (tid < 256) {
    int n = tid >> 2, ds = tid & 3;
    float4 g4 = *(float4*)&gl[n >> 4][n & 15][ds * 4];
    int d = d0 + ds;
    float I = sigm(g4.x + bsum1[d]);
    float F = sigm(g4.y + bsum1[1024 + d]);
    float G = ftanh(g4.z + bsum1[2048 + d]);
    float O = sigm(g4.w + bsum1[3072 + d]);
    float cv = F * c1[n * 1024 + d] + I * G;
    c1[n * 1024 + d] = cv;
    h1nxt[n * 1024 + d] = __float2bfloat16(O * ftanh(cv));
  }
}

// ---------------------------------------------------------------- k_ca
// grid 64 (one batch row each), block 512. LSTM2 (thread = gate row) then
// attention for step t+1 with the fresh h2 (LDS).
__global__ __launch_bounds__(512) void k_ca(
    const __hip_bfloat16* __restrict__ h1nxt, __hip_bfloat16* __restrict__ h2g,
    float* __restrict__ c2, const __hip_bfloat16* __restrict__ W2T,
    const float* __restrict__ bsum2, const float* __restrict__ key,
    const float* __restrict__ value, const __hip_bfloat16* __restrict__ keybf,
    const __hip_bfloat16* __restrict__ valbf, int kv, const int* __restrict__ slen,
    __hip_bfloat16* __restrict__ ctxbf, __hip_bfloat16* __restrict__ h2cbf, int t) {
  int n = blockIdx.x, tid = threadIdx.x;
  __shared__ float h1s[1024];
  __shared__ float h2s[128], h2n[128];
  __shared__ float g2[512];
  __shared__ float e_l[512];
  __shared__ float red[512];
  __shared__ float ctxp[4][128];

  {  // stage h1 row (1024 bf16) and previous h2 (128 bf16)
    unsigned u = *(const unsigned*)((const unsigned short*)h1nxt + (size_t)n * 1024 + tid * 2);
    h1s[tid * 2] = bf2f(u & 0xffffu);
    h1s[tid * 2 + 1] = bf2f(u >> 16);
  }
  if (tid < 128) h2s[tid] = __bfloat162float(h2g[n * 128 + tid]);
  __syncthreads();

  {  // lstm2: thread owns gate row tid
    float acc = 0.f;
    #pragma unroll 4
    for (int kb = 0; kb < 144; ++kb) {
      uint4 wv = *(const uint4*)(W2T + ((size_t)kb * 512 + tid) * 8);
      const float* in = (kb < 128) ? &h1s[kb * 8] : &h2s[(kb - 128) * 8];
      acc += bf2f(wv.x & 0xffffu) * in[0] + bf2f(wv.x >> 16) * in[1]
           + bf2f(wv.y & 0xffffu) * in[2] + bf2f(wv.y >> 16) * in[3]
           + bf2f(wv.z & 0xffffu) * in[4] + bf2f(wv.z >> 16) * in[5]
           + bf2f(wv.w & 0xffffu) * in[6] + bf2f(wv.w >> 16) * in[7];
    }
    g2[tid] = acc;
  }
  __syncthreads();
  if (tid < 128) {
    int d = tid;
    float I = sigm(g2[d] + bsum2[d]);
    float F = sigm(g2[128 + d] + bsum2[128 + d]);
    float G = ftanh(g2[256 + d] + bsum2[256 + d]);
    float O = sigm(g2[384 + d] + bsum2[384 + d]);
    float cv = F * c2[n * 128 + d] + I * G;
    c2[n * 128 + d] = cv;
    float h = O * ftanh(cv);
    h2n[d] = h;
    __hip_bfloat16 hb = __float2bfloat16(h);
    h2g[n * 128 + d] = hb;
    h2cbf[((size_t)t * NB + n) * 256 + d] = hb;
  }
  __syncthreads();

  if (t < TDEC - 1) {  // attention for step t+1
    int len = slen[n];
    float e = -INFINITY;
    if (tid < len) {
      float s = 0.f;
      if (kv) {
        const uint4* kr = (const uint4*)(keybf + ((size_t)n * TENC + tid) * KSZ);
        #pragma unroll
        for (int kk = 0; kk < 16; ++kk) {
          uint4 u = kr[kk];
          const float* hh = &h2n[kk * 8];
          s += bf2f(u.x & 0xffffu) * hh[0] + bf2f(u.x >> 16) * hh[1]
             + bf2f(u.y & 0xffffu) * hh[2] + bf2f(u.y >> 16) * hh[3]
             + bf2f(u.z & 0xffffu) * hh[4] + bf2f(u.z >> 16) * hh[5]
             + bf2f(u.w & 0xffffu) * hh[6] + bf2f(u.w >> 16) * hh[7];
        }
      } else {
        const float4* kr = (const float4*)(key + ((size_t)n * TENC + tid) * KSZ);
        #pragma unroll 8
        for (int kk = 0; kk < 32; ++kk) {
          float4 u = kr[kk];
          const float* hh = &h2n[kk * 4];
          s += u.x * hh[0] + u.y * hh[1] + u.z * hh[2] + u.w * hh[3];
        }
      }
      e = s;
    }
    red[tid] = e;
    __syncthreads();
    for (int s2 = 256; s2 > 0; s2 >>= 1) {
      if (tid < s2) red[tid] = fmaxf(red[tid], red[tid + s2]);
      __syncthreads();
    }
    float m = red[0];
    __syncthreads();
    float ex = (tid < len) ? __expf(e - m) : 0.f;
    e_l[tid] = ex;
    red[tid] = ex;
    __syncthreads();
    for (int s2 = 256; s2 > 0; s2 >>= 1) {
      if (tid < s2) red[tid] += red[tid + s2];
      __syncthreads();
    }
    float inv = 1.f / red[0];
    {
      int v = tid & 127, ph = tid >> 7;
      float acc = 0.f;
      if (kv) {
        const unsigned short* vb = (const unsigned short*)valbf;
        for (int p = ph; p < len; p += 4)
          acc += e_l[p] * bf2f(vb[((size_t)n * TENC + p) * VSZ + v]);
      } else {
        for (int p = ph; p < len; p += 4)
          acc += e_l[p] * value[((size_t)n * TENC + p) * VSZ + v];
      }
      ctxp[ph][v] = acc;
    }
    __syncthreads();
    if (tid < 128) {
      float c = (ctxp[0][tid] + ctxp[1][tid] + ctxp[2][tid] + ctxp[3][tid]) * inv;
      __hip_bfloat16 cb = __float2bfloat16(c);
      ctxbf[n * 128 + tid] = cb;
      h2cbf[((size_t)(t + 1) * NB + n) * 256 + 128 + tid] = cb;
    }
  }
}

// ------------------------------------------------------ output projection
__global__ __launch_bounds__(256) void k_out(const __hip_bfloat16* __restrict__ h2cbf,
                                             const __hip_bfloat16* __restrict__ Woutbf,
                                             const float* __restrict__ bout,
                                             float* __restrict__ out) {
  int tid = threadIdx.x;
  int w = tid >> 6, lane = tid & 63;
  int ln15 = lane & 15, lg = lane >> 4, ko = lg * 8;
  int c0 = blockIdx.x * 64, m0 = blockIdx.y * 64;
  const __hip_bfloat16* ap = h2cbf + (size_t)(m0 + w * 16 + ln15) * 256;
  bf16x8 afr[8];
  #pragma unroll
  for (int kk = 0; kk < 8; ++kk) afr[kk] = ldfrag(ap + kk * 32 + ko);
  union U16 { uint4 u; bf16x8 v; };
  #pragma unroll
  for (int s = 0; s < 4; ++s) {
    int r = c0 + s * 16 + ln15;
    const __hip_bfloat16* bp = Woutbf + (size_t)r * 256;
    bool ok = r < VOCAB;
    f32x4 acc = {0.f, 0.f, 0.f, 0.f};
    #pragma unroll
    for (int kk = 0; kk < 8; ++kk) {
      U16 bv;
      bv.u = make_uint4(0, 0, 0, 0);
      if (ok) bv.v = ldfrag(bp + kk * 32 + ko);
      acc = MFMA16(afr[kk], bv.v, acc);
    }
    int c = c0 + s * 16 + ln15;
    if (c < VOCAB) {
      float bb = bout[c];
      #pragma unroll
      for (int reg = 0; reg < 4; ++reg) {
        int m = m0 + w * 16 + 4 * lg + reg;
        int n = m & 63, tt = m >> 6;
        out[((size_t)n * TDEC + tt) * VOCAB + c] = acc[reg] + bb;
      }
    }
  }
}

// ---------------------------------------------------------------------------
extern "C" void kernel_launch(void* const* d_in, const int* in_sizes, int n_in,
                              void* d_out, int out_size, void* d_ws, size_t ws_size,
                              hipStream_t stream) {
  (void)in_sizes; (void)n_in; (void)out_size;
  const float* key   = (const float*)d_in[0];
  const float* value = (const float*)d_in[1];
  const int*   slen  = (const int*)d_in[2];
  const int*   text  = (const int*)d_in[3];
  const float* emb   = (const float*)d_in[4];
  const float* Wih1  = (const float*)d_in[5];
  const float* Whh1  = (const float*)d_in[6];
  const float* bih1  = (const float*)d_in[7];
  const float* bhh1  = (const float*)d_in[8];
  const float* Wih2  = (const float*)d_in[9];
  const float* Whh2  = (const float*)d_in[10];
  const float* bih2  = (const float*)d_in[11];
  const float* bhh2  = (const float*)d_in[12];
  const float* Wout  = (const float*)d_in[13];
  const float* bout  = (const float*)d_in[14];
  float* out = (float*)d_out;
  char* ws = (char*)d_ws;

  __hip_bfloat16* h1T    = (__hip_bfloat16*)(ws + OFF_H1);
  __hip_bfloat16* h2g    = (__hip_bfloat16*)(ws + OFF_H2G);
  float*          c1     = (float*)(ws + OFF_C1);
  float*          c2     = (float*)(ws + OFF_C2);
  __hip_bfloat16* ctxbf  = (__hip_bfloat16*)(ws + OFF_CTX);
  float*          bsum1  = (float*)(ws + OFF_BS1);
  float*          bsum2  = (float*)(ws + OFF_BS2);
  __hip_bfloat16* W2T    = (__hip_bfloat16*)(ws + OFF_W2T);
  __hip_bfloat16* W1bf   = (__hip_bfloat16*)(ws + OFF_W1);
  __hip_bfloat16* Woutbf = (__hip_bfloat16*)(ws + OFF_WOUT);
  __hip_bfloat16* xembbf = (__hip_bfloat16*)(ws + OFF_XEMB);
  __hip_bfloat16* h2cbf  = (__hip_bfloat16*)(ws + OFF_H2C);
  int kv = (ws_size >= KV_END) ? 1 : 0;
  __hip_bfloat16* keybf  = (__hip_bfloat16*)(ws + OFF_KEYBF);
  __hip_bfloat16* valbf  = (__hip_bfloat16*)(ws + OFF_VALBF);

  hipMemsetAsync(d_ws, 0, ZERO_END, stream);  // h1 both buffers, h2g, c1, c2
  k_prep_w1<<<4096, 256, 0, stream>>>(Wih1, Whh1, bih1, bhh1, W1bf, bsum1);
  k_prep_w2t<<<512, 256, 0, stream>>>(Wih2, Whh2, bih2, bhh2, W2T, bsum2);
  k_prep_wout<<<625, 256, 0, stream>>>(Wout, Woutbf);
  k_gather<<<TDEC, 256, 0, stream>>>(text, emb, xembbf);
  if (kv) k_prep_kv<<<2048, 256, 0, stream>>>(key, value, keybf, valbf);
  k_ctx0<<<NB, 256, 0, stream>>>(value, valbf, kv, slen, ctxbf, h2cbf);

  for (int t = 0; t < TDEC; ++t) {
    const __hip_bfloat16* h1cur = h1T + (size_t)(t & 1) * (NB * HID);
    __hip_bfloat16*       h1nxt = h1T + (size_t)((t + 1) & 1) * (NB * HID);
    k_lstm1<<<256, 512, 0, stream>>>(xembbf, ctxbf, h1cur, h1nxt, c1, W1bf, bsum1, t);
    k_ca<<<NB, 512, 0, stream>>>(h1nxt, h2g, c2, W2T, bsum2, key, value,
                                 keybf, valbf, kv, slen, ctxbf, h2cbf, t);
  }

  k_out<<<dim3(157, 200), 256, 0, stream>>>(h2cbf, Woutbf, bout, out);
}